// Round 1
// baseline (1121.449 us; speedup 1.0000x reference)
//
#include <hip/hip_runtime.h>
#include <cstddef>
#include <cstdint>
#include <math.h>

// ---------------- problem constants ----------------
constexpr int Bb   = 8;
constexpr int Ll   = 2048;
constexpr int Hin  = 128;
constexpr int Dm   = 512;
constexpr int Mrows = Bb * Ll;          // 16384
constexpr int NC   = 32;                // scan chunks per sequence
constexpr int CL   = Ll / NC;           // 64 timesteps per chunk
constexpr int SZ1  = Bb * NC * Dm;      // 131072 per state component

// ---------------- device math helpers ----------------
static __device__ __forceinline__ float sigmoid_f(float x) {
    return 1.f / (1.f + expf(-x));
}
static __device__ __forceinline__ float gelu_tanh_f(float x) {
    // jax.nn.gelu default (approximate=True)
    float x3 = x * x * x;
    float t  = tanhf(0.7978845608028654f * (x + 0.044715f * x3));
    return 0.5f * x * (1.f + t);
}

// ---------------- fused GEMM ----------------
// C[M,N] = epilogue( A[M,K] @ W[N,K]^T , ... )
// KM=0: C = A@W^T + bias (bias may be null)
// KM=1: C = gelu( A@W^T - A2@W2^T + DV[col]*EX[row,col] )       (C-projection)
// KM=2: C = EX + (A@W^T + bias) * sigmoid(A@W2^T + bias2)        (GLU + skip)
template <int KM>
__global__ __launch_bounds__(256) void gemm_fused(
    const float* __restrict__ A, const float* __restrict__ A2,
    const float* __restrict__ W, const float* __restrict__ W2,
    const float* __restrict__ bias, const float* __restrict__ bias2,
    const float* __restrict__ EX, const float* __restrict__ DV,
    float* __restrict__ C, int M, int N, int K)
{
    constexpr int BM = 128, BN = 64, BK = 16;
    constexpr int AP = BM + 4;   // padded LDS row (transposed tiles)
    constexpr int WP = BN + 4;
    constexpr int AW = BK * AP;  // 2112 words
    constexpr int WW = BK * WP;  // 1088 words

    extern __shared__ float smem[];
    float (*AsT)[AP]  = reinterpret_cast<float(*)[AP]>(smem);
    float (*A2sT)[AP] = reinterpret_cast<float(*)[AP]>(smem + AW);
    float (*WsT)[WP]  = reinterpret_cast<float(*)[WP]>(smem + (KM == 1 ? 2 * AW : AW));
    float (*W2sT)[WP] = reinterpret_cast<float(*)[WP]>(smem + (KM == 1 ? 2 * AW + WW : AW + WW));

    const int tid = threadIdx.x;
    const int tx  = tid & 15;        // 0..15 -> output col group
    const int ty  = tid >> 4;        // 0..15 -> output row group
    const int row0 = blockIdx.x * BM;
    const int col0 = blockIdx.y * BN;

    float acc[8][4];
    float acc2[8][4];
#pragma unroll
    for (int i = 0; i < 8; ++i)
#pragma unroll
        for (int j = 0; j < 4; ++j) { acc[i][j] = 0.f; acc2[i][j] = 0.f; }

    for (int k0 = 0; k0 < K; k0 += BK) {
        __syncthreads();
        // stage A tile(s): global [row][k] -> LDS transposed [k][row]
#pragma unroll
        for (int li = tid; li < BM * BK / 4; li += 256) {
            const int r  = li >> 2;
            const int k4 = (li & 3) << 2;
            const float4 v = *(const float4*)(A + (size_t)(row0 + r) * K + k0 + k4);
            AsT[k4 + 0][r] = v.x; AsT[k4 + 1][r] = v.y;
            AsT[k4 + 2][r] = v.z; AsT[k4 + 3][r] = v.w;
            if (KM == 1) {
                const float4 u = *(const float4*)(A2 + (size_t)(row0 + r) * K + k0 + k4);
                A2sT[k4 + 0][r] = u.x; A2sT[k4 + 1][r] = u.y;
                A2sT[k4 + 2][r] = u.z; A2sT[k4 + 3][r] = u.w;
            }
        }
        // stage W tile(s)
        {
            const int c  = tid >> 2;
            const int k4 = (tid & 3) << 2;
            const float4 v = *(const float4*)(W + (size_t)(col0 + c) * K + k0 + k4);
            WsT[k4 + 0][c] = v.x; WsT[k4 + 1][c] = v.y;
            WsT[k4 + 2][c] = v.z; WsT[k4 + 3][c] = v.w;
            if (KM >= 1) {
                const float4 u = *(const float4*)(W2 + (size_t)(col0 + c) * K + k0 + k4);
                W2sT[k4 + 0][c] = u.x; W2sT[k4 + 1][c] = u.y;
                W2sT[k4 + 2][c] = u.z; W2sT[k4 + 3][c] = u.w;
            }
        }
        __syncthreads();

#pragma unroll
        for (int kk = 0; kk < BK; ++kk) {
            float a[8], w[4], a2v[8], w2v[4];
            *(float4*)&a[0] = *(const float4*)&AsT[kk][ty * 8];
            *(float4*)&a[4] = *(const float4*)&AsT[kk][ty * 8 + 4];
            *(float4*)&w[0] = *(const float4*)&WsT[kk][tx * 4];
            if (KM == 1) {
                *(float4*)&a2v[0] = *(const float4*)&A2sT[kk][ty * 8];
                *(float4*)&a2v[4] = *(const float4*)&A2sT[kk][ty * 8 + 4];
                *(float4*)&w2v[0] = *(const float4*)&W2sT[kk][tx * 4];
            }
            if (KM == 2) {
                *(float4*)&w2v[0] = *(const float4*)&W2sT[kk][tx * 4];
            }
#pragma unroll
            for (int i = 0; i < 8; ++i)
#pragma unroll
                for (int j = 0; j < 4; ++j) {
                    if (KM == 0) {
                        acc[i][j] = fmaf(a[i], w[j], acc[i][j]);
                    } else if (KM == 1) {
                        acc[i][j] = fmaf(a[i], w[j], fmaf(-a2v[i], w2v[j], acc[i][j]));
                    } else {
                        acc[i][j]  = fmaf(a[i], w[j],  acc[i][j]);
                        acc2[i][j] = fmaf(a[i], w2v[j], acc2[i][j]);
                    }
                }
        }
    }

    // ---------------- epilogue ----------------
    const int cbase = col0 + tx * 4;
    if (KM == 0) {
        float4 bv = make_float4(0.f, 0.f, 0.f, 0.f);
        if (bias) bv = *(const float4*)(bias + cbase);
#pragma unroll
        for (int i = 0; i < 8; ++i) {
            const int r = row0 + ty * 8 + i;
            float4 o;
            o.x = acc[i][0] + bv.x; o.y = acc[i][1] + bv.y;
            o.z = acc[i][2] + bv.z; o.w = acc[i][3] + bv.w;
            *(float4*)(C + (size_t)r * N + cbase) = o;
        }
    } else if (KM == 1) {
        const float4 dv = *(const float4*)(DV + cbase);
#pragma unroll
        for (int i = 0; i < 8; ++i) {
            const int r = row0 + ty * 8 + i;
            const float4 hv = *(const float4*)(EX + (size_t)r * N + cbase);
            float4 o;
            o.x = gelu_tanh_f(acc[i][0] + dv.x * hv.x);
            o.y = gelu_tanh_f(acc[i][1] + dv.y * hv.y);
            o.z = gelu_tanh_f(acc[i][2] + dv.z * hv.z);
            o.w = gelu_tanh_f(acc[i][3] + dv.w * hv.w);
            *(float4*)(C + (size_t)r * N + cbase) = o;
        }
    } else {
        const float4 b1 = *(const float4*)(bias  + cbase);
        const float4 b2 = *(const float4*)(bias2 + cbase);
#pragma unroll
        for (int i = 0; i < 8; ++i) {
            const int r = row0 + ty * 8 + i;
            const float4 sv = *(const float4*)(EX + (size_t)r * N + cbase);
            float4 o;
            o.x = sv.x + (acc[i][0] + b1.x) * sigmoid_f(acc2[i][0] + b2.x);
            o.y = sv.y + (acc[i][1] + b1.y) * sigmoid_f(acc2[i][1] + b2.y);
            o.z = sv.z + (acc[i][2] + b1.z) * sigmoid_f(acc2[i][2] + b2.z);
            o.w = sv.w + (acc[i][3] + b1.w) * sigmoid_f(acc2[i][3] + b2.w);
            *(float4*)(C + (size_t)r * N + cbase) = o;
        }
    }
}

// ---------------- LayerNorm (rows of 512) ----------------
__global__ __launch_bounds__(256) void layernorm_k(
    const float* __restrict__ X, const float* __restrict__ g,
    const float* __restrict__ b, float* __restrict__ Y)
{
    const int lane = threadIdx.x & 63;
    const int w    = threadIdx.x >> 6;
    const int row  = blockIdx.x * 4 + w;
    const size_t base = (size_t)row * Dm;

    const float4 v0 = *(const float4*)(X + base + lane * 4);
    const float4 v1 = *(const float4*)(X + base + 256 + lane * 4);
    float s = v0.x + v0.y + v0.z + v0.w + v1.x + v1.y + v1.z + v1.w;
    float q = v0.x * v0.x + v0.y * v0.y + v0.z * v0.z + v0.w * v0.w +
              v1.x * v1.x + v1.y * v1.y + v1.z * v1.z + v1.w * v1.w;
#pragma unroll
    for (int off = 32; off > 0; off >>= 1) {
        s += __shfl_xor(s, off);
        q += __shfl_xor(q, off);
    }
    const float mu  = s * (1.f / 512.f);
    const float var = q * (1.f / 512.f) - mu * mu;
    const float rs  = rsqrtf(var + 1e-5f);

    const float4 g0 = *(const float4*)(g + lane * 4);
    const float4 g1 = *(const float4*)(g + 256 + lane * 4);
    const float4 b0 = *(const float4*)(b + lane * 4);
    const float4 b1 = *(const float4*)(b + 256 + lane * 4);
    float4 o0, o1;
    o0.x = (v0.x - mu) * rs * g0.x + b0.x;
    o0.y = (v0.y - mu) * rs * g0.y + b0.y;
    o0.z = (v0.z - mu) * rs * g0.z + b0.z;
    o0.w = (v0.w - mu) * rs * g0.w + b0.w;
    o1.x = (v1.x - mu) * rs * g1.x + b1.x;
    o1.y = (v1.y - mu) * rs * g1.y + b1.y;
    o1.z = (v1.z - mu) * rs * g1.z + b1.z;
    o1.w = (v1.w - mu) * rs * g1.w + b1.w;
    *(float4*)(Y + base + lane * 4) = o0;
    *(float4*)(Y + base + 256 + lane * 4) = o1;
}

// ---------------- scan constants ----------------
// cst layout: [m11][m12][m21][m22][c1=m11*dt][c2=m21*dt], each Dm floats
__global__ void consts_k(const float* __restrict__ A_diag,
                         const float* __restrict__ log_steps,
                         float* __restrict__ cst)
{
    const int n = threadIdx.x;
    const float a   = fmaxf(A_diag[n], 0.f);
    const float dt  = 1.f / (1.f + expf(-log_steps[n]));
    const float d2a = dt * dt * a;
    const float S   = 1.f / (1.f + d2a);
    const float m11 = 1.f - d2a * S;
    const float m12 = -dt * a * S;
    const float m21 = dt * S;
    const float m22 = S;
    cst[n]            = m11;
    cst[Dm + n]       = m12;
    cst[2 * Dm + n]   = m21;
    cst[3 * Dm + n]   = m22;
    cst[4 * Dm + n]   = m11 * dt;
    cst[5 * Dm + n]   = m21 * dt;
}

// ---------------- scan phase 1: per-chunk local final states ----------------
__global__ __launch_bounds__(512) void scan_phase1(
    const float* __restrict__ bur, const float* __restrict__ bui,
    const float* __restrict__ cst, float* __restrict__ S1)
{
    const int n = threadIdx.x;
    const int c = blockIdx.x & (NC - 1);
    const int b = blockIdx.x >> 5;
    const float m11 = cst[n],          m12 = cst[Dm + n];
    const float m21 = cst[2 * Dm + n], m22 = cst[3 * Dm + n];
    const float c1  = cst[4 * Dm + n], c2  = cst[5 * Dm + n];

    float zr = 0.f, xr = 0.f, zi = 0.f, xi = 0.f;
    const size_t base = ((size_t)b * Ll + (size_t)c * CL) * Dm + n;
#pragma unroll 4
    for (int t = 0; t < CL; ++t) {
        const float br = bur[base + (size_t)t * Dm];
        const float bi = bui[base + (size_t)t * Dm];
        const float zrn = fmaf(m11, zr, fmaf(m12, xr, c1 * br));
        const float xrn = fmaf(m21, zr, fmaf(m22, xr, c2 * br));
        const float zin = fmaf(m11, zi, fmaf(m12, xi, c1 * bi));
        const float xin = fmaf(m21, zi, fmaf(m22, xi, c2 * bi));
        zr = zrn; xr = xrn; zi = zin; xi = xin;
    }
    const int idx = blockIdx.x * Dm + n;
    S1[idx]            = zr;
    S1[SZ1 + idx]      = xr;
    S1[2 * SZ1 + idx]  = zi;
    S1[3 * SZ1 + idx]  = xi;
}

// ---------------- scan phase 2: inter-chunk exclusive scan ----------------
__global__ __launch_bounds__(256) void scan_phase2(
    const float* __restrict__ S1, const float* __restrict__ cst,
    float* __restrict__ G)
{
    const int gidx = blockIdx.x * 256 + threadIdx.x; // 0..4095
    const int n = gidx & (Dm - 1);
    const int b = gidx >> 9;
    const float m11 = cst[n],          m12 = cst[Dm + n];
    const float m21 = cst[2 * Dm + n], m22 = cst[3 * Dm + n];

    // P = M^CL
    float p11 = 1.f, p12 = 0.f, p21 = 0.f, p22 = 0.f;
    p22 = 1.f;
    for (int i = 0; i < CL; ++i) {
        const float q11 = m11 * p11 + m12 * p21;
        const float q12 = m11 * p12 + m12 * p22;
        const float q21 = m21 * p11 + m22 * p21;
        const float q22 = m21 * p12 + m22 * p22;
        p11 = q11; p12 = q12; p21 = q21; p22 = q22;
    }

    float gzr = 0.f, gxr = 0.f, gzi = 0.f, gxi = 0.f;
    for (int c = 0; c < NC; ++c) {
        const int idx = (b * NC + c) * Dm + n;
        G[idx]           = gzr;
        G[SZ1 + idx]     = gxr;
        G[2 * SZ1 + idx] = gzi;
        G[3 * SZ1 + idx] = gxi;
        const float szr = S1[idx],           sxr = S1[SZ1 + idx];
        const float szi = S1[2 * SZ1 + idx], sxi = S1[3 * SZ1 + idx];
        const float t1 = p11 * gzr + p12 * gxr + szr;
        const float t2 = p21 * gzr + p22 * gxr + sxr;
        const float t3 = p11 * gzi + p12 * gxi + szi;
        const float t4 = p21 * gzi + p22 * gxi + sxi;
        gzr = t1; gxr = t2; gzi = t3; gxi = t4;
    }
}

// ---------------- scan phase 3: re-scan with incoming state; in-place Bu -> xs ----------------
__global__ __launch_bounds__(512) void scan_phase3(
    float* __restrict__ bur, float* __restrict__ bui,
    const float* __restrict__ cst, const float* __restrict__ G)
{
    const int n = threadIdx.x;
    const int c = blockIdx.x & (NC - 1);
    const int b = blockIdx.x >> 5;
    const float m11 = cst[n],          m12 = cst[Dm + n];
    const float m21 = cst[2 * Dm + n], m22 = cst[3 * Dm + n];
    const float c1  = cst[4 * Dm + n], c2  = cst[5 * Dm + n];

    const int sidx = blockIdx.x * Dm + n;
    float zr = G[sidx];
    float xr = G[SZ1 + sidx];
    float zi = G[2 * SZ1 + sidx];
    float xi = G[3 * SZ1 + sidx];

    const size_t base = ((size_t)b * Ll + (size_t)c * CL) * Dm + n;
#pragma unroll 4
    for (int t = 0; t < CL; ++t) {
        const float br = bur[base + (size_t)t * Dm];
        const float bi = bui[base + (size_t)t * Dm];
        const float zrn = fmaf(m11, zr, fmaf(m12, xr, c1 * br));
        const float xrn = fmaf(m21, zr, fmaf(m22, xr, c2 * br));
        const float zin = fmaf(m11, zi, fmaf(m12, xi, c1 * bi));
        const float xin = fmaf(m21, zi, fmaf(m22, xi, c2 * bi));
        zr = zrn; xr = xrn; zi = zin; xi = xin;
        bur[base + (size_t)t * Dm] = xr;  // xs real (in place)
        bui[base + (size_t)t * Dm] = xi;  // xs imag (in place)
    }
}

// ---------------- launch ----------------
extern "C" void kernel_launch(void* const* d_in, const int* in_sizes, int n_in,
                              void* d_out, int out_size, void* d_ws, size_t ws_size,
                              hipStream_t stream)
{
    const float* x         = (const float*)d_in[0];
    const float* W_in      = (const float*)d_in[1];
    const float* b_in      = (const float*)d_in[2];
    const float* W_enc     = (const float*)d_in[3];
    const float* b_enc     = (const float*)d_in[4];
    const float* ln_g      = (const float*)d_in[5];
    const float* ln_b      = (const float*)d_in[6];
    const float* A_diag    = (const float*)d_in[7];
    const float* log_steps = (const float*)d_in[8];
    const float* B_re      = (const float*)d_in[9];
    const float* B_im      = (const float*)d_in[10];
    const float* C_re      = (const float*)d_in[11];
    const float* C_im      = (const float*)d_in[12];
    const float* Dv        = (const float*)d_in[13];
    const float* glu_w1    = (const float*)d_in[14];
    const float* glu_b1    = (const float*)d_in[15];
    const float* glu_w2    = (const float*)d_in[16];
    const float* glu_b2    = (const float*)d_in[17];
    const float* W_dec     = (const float*)d_in[18];
    const float* b_dec     = (const float*)d_in[19];
    const float* W_out     = (const float*)d_in[20];
    const float* b_out     = (const float*)d_in[21];

    char* ws = (char*)d_ws;
    const size_t SZ = (size_t)Mrows * Dm * sizeof(float); // 32 MB
    float* buf0 = (float*)(ws);            // h1 -> g
    float* buf1 = (float*)(ws + SZ);       // skip -> h3
    float* buf2 = (float*)(ws + 2 * SZ);   // hn -> h2
    float* buf3 = (float*)(ws + 3 * SZ);   // Bu_re -> xs_re
    float* buf4 = (float*)(ws + 4 * SZ);   // Bu_im -> xs_im
    float* S1   = (float*)(ws + 5 * SZ);   // 4*SZ1 floats
    float* G    = S1 + 4 * SZ1;            // 4*SZ1 floats
    float* cst  = G + 4 * SZ1;             // 6*Dm floats

    constexpr int AW = 16 * 132, WW = 16 * 68;
    const size_t sm0 = (size_t)(AW + WW) * 4;
    const size_t sm1 = (size_t)(2 * AW + 2 * WW) * 4;
    const size_t sm2 = (size_t)(AW + 2 * WW) * 4;

    dim3 blk(256);
    dim3 g512(Mrows / 128, Dm / 64);
    dim3 g128(Mrows / 128, Hin / 64);

    consts_k<<<1, Dm, 0, stream>>>(A_diag, log_steps, cst);

    // h1 = x @ W_in^T + b_in
    gemm_fused<0><<<g512, blk, sm0, stream>>>(x, nullptr, W_in, nullptr, b_in, nullptr,
                                              nullptr, nullptr, buf0, Mrows, Dm, Hin);
    // skip = h1 @ W_enc^T + b_enc
    gemm_fused<0><<<g512, blk, sm0, stream>>>(buf0, nullptr, W_enc, nullptr, b_enc, nullptr,
                                              nullptr, nullptr, buf1, Mrows, Dm, Dm);
    // hn = layernorm(skip)
    layernorm_k<<<Mrows / 4, 256, 0, stream>>>(buf1, ln_g, ln_b, buf2);
    // Bu_re = hn @ B_re^T ; Bu_im = hn @ B_im^T
    gemm_fused<0><<<g512, blk, sm0, stream>>>(buf2, nullptr, B_re, nullptr, nullptr, nullptr,
                                              nullptr, nullptr, buf3, Mrows, Dm, Dm);
    gemm_fused<0><<<g512, blk, sm0, stream>>>(buf2, nullptr, B_im, nullptr, nullptr, nullptr,
                                              nullptr, nullptr, buf4, Mrows, Dm, Dm);
    // LinOSS scan (IM discretization, constant per-channel 2x2 transition)
    scan_phase1<<<Bb * NC, 512, 0, stream>>>(buf3, buf4, cst, S1);
    scan_phase2<<<(Bb * Dm) / 256, 256, 0, stream>>>(S1, cst, G);
    scan_phase3<<<Bb * NC, 512, 0, stream>>>(buf3, buf4, cst, G);
    // g = gelu(xs_re @ C_re^T - xs_im @ C_im^T + D*hn)
    gemm_fused<1><<<g512, blk, sm1, stream>>>(buf3, buf4, C_re, C_im, nullptr, nullptr,
                                              buf2, Dv, buf0, Mrows, Dm, Dm);
    // h2 = skip + (g@w1^T+b1)*sigmoid(g@w2^T+b2)
    gemm_fused<2><<<g512, blk, sm2, stream>>>(buf0, nullptr, glu_w1, glu_w2, glu_b1, glu_b2,
                                              buf1, nullptr, buf2, Mrows, Dm, Dm);
    // h3 = h2 @ W_dec^T + b_dec
    gemm_fused<0><<<g512, blk, sm0, stream>>>(buf2, nullptr, W_dec, nullptr, b_dec, nullptr,
                                              nullptr, nullptr, buf1, Mrows, Dm, Dm);
    // out = h3 @ W_out^T + b_out
    gemm_fused<0><<<g128, blk, sm0, stream>>>(buf1, nullptr, W_out, nullptr, b_out, nullptr,
                                              nullptr, nullptr, (float*)d_out, Mrows, Hin, Dm);
}

// Round 3
// 353.195 us; speedup vs baseline: 3.1752x; 3.1752x over previous
//
#include <hip/hip_runtime.h>
#include <cstddef>
#include <cstdint>
#include <math.h>

typedef _Float16 f16;
typedef f16 f16x8 __attribute__((ext_vector_type(8)));
typedef f16 f16x4 __attribute__((ext_vector_type(4)));
typedef float f32x4 __attribute__((ext_vector_type(4)));

// ---------------- problem constants ----------------
constexpr int Bb   = 8;
constexpr int Ll   = 2048;
constexpr int Hin  = 128;
constexpr int Dm   = 512;
constexpr int Mrows = Bb * Ll;          // 16384
constexpr int NC   = 32;                // scan chunks per sequence
constexpr int CL   = Ll / NC;           // 64 timesteps per chunk
constexpr int SZ1  = Bb * NC * Dm;      // 131072 per state component

// LDS tile: 128 rows x 32 k, padded to 40 f16 per row (80B stride -> conflict-free)
constexpr int TPAD = 40;
constexpr int TILE_ELE = 128 * TPAD;    // 5120 f16 per tile

// ---------------- device math helpers ----------------
static __device__ __forceinline__ float sigmoid_f(float x) {
    return 1.f / (1.f + expf(-x));
}
static __device__ __forceinline__ float gelu_tanh_f(float x) {
    float x3 = x * x * x;
    float t  = tanhf(0.7978845608028654f * (x + 0.044715f * x3));
    return 0.5f * x * (1.f + t);
}

// ---------------- weight/x fp32 -> f16 conversion ----------------
struct CvtJob { const float* s; f16* d; int n; };
struct CvtJobs { CvtJob j[11]; };

__global__ __launch_bounds__(256) void convert_k(CvtJobs jobs) {
    const CvtJob jb = jobs.j[blockIdx.y];
    const int i = (blockIdx.x * 256 + threadIdx.x) * 4;
    if (i >= jb.n) return;
    const float4 v = *(const float4*)(jb.s + i);
    f16x4 o;
    o.x = (f16)v.x; o.y = (f16)v.y; o.z = (f16)v.z; o.w = (f16)v.w;
    *(f16x4*)(jb.d + i) = o;
}

// ---------------- fused MFMA GEMM ----------------
// C[M,N] = epilogue( A[M,K] @ W[N,K]^T )
// KM=0: C = A@W^T + bias (bias may be null)
// KM=1: C = gelu( A@W^T + A2@W2^T + DV[col]*EX )   (A2 pre-negated imag part)
// KM=2: C = EX + (A@W^T + bias)*sigmoid(A@W2^T + bias2)
template <int KM, int OUTF16>
__global__ __launch_bounds__(256) void gemm_mfma(
    const f16* __restrict__ A, const f16* __restrict__ A2,
    const f16* __restrict__ W, const f16* __restrict__ W2,
    const float* __restrict__ bias, const float* __restrict__ bias2,
    const f16* __restrict__ EX, const float* __restrict__ DV,
    void* __restrict__ Cout, int M, int N, int K)
{
    constexpr int NT = (KM == 1) ? 4 : (KM == 2) ? 3 : 2;
    __shared__ f16 smem[NT * TILE_ELE];
    f16* As  = smem;
    f16* As2 = (KM == 1) ? smem + TILE_ELE : nullptr;
    f16* Bs  = smem + ((KM == 1) ? 2 : 1) * TILE_ELE;
    f16* Bs2 = (KM >= 1) ? smem + ((KM == 1) ? 3 : 2) * TILE_ELE : nullptr;

    const int tid = threadIdx.x;
    const int l   = tid & 63;
    const int wid = tid >> 6;       // 0..3
    const int wr  = wid >> 1;       // 0..1 row half
    const int wc  = wid & 1;        // 0..1 col half
    const int lr  = l >> 4;         // 0..3
    const int lc  = l & 15;
    const int row0 = blockIdx.x * 128;
    const int col0 = blockIdx.y * 128;

    f32x4 acc[4][4];
    f32x4 acc2[(KM == 2) ? 4 : 1][(KM == 2) ? 4 : 1];
#pragma unroll
    for (int i = 0; i < 4; ++i)
#pragma unroll
        for (int j = 0; j < 4; ++j) {
            acc[i][j] = (f32x4){0.f, 0.f, 0.f, 0.f};
            if (KM == 2) acc2[i][j] = (f32x4){0.f, 0.f, 0.f, 0.f};
        }

    // per-thread staging coords: chunk c = tid + h*256; row = c>>2, g = c&3
    const int sr0 = tid >> 2, sg0 = tid & 3;
    const int sr1 = (tid + 256) >> 2, sg1 = tid & 3;

    const f16* abase = As + (wr * 64 + lc) * TPAD + lr * 8;
    const f16* bbase = Bs + (wc * 64 + lc) * TPAD + lr * 8;

    for (int k0 = 0; k0 < K; k0 += 32) {
        __syncthreads();
        {
            *(f16x8*)(As + sr0 * TPAD + sg0 * 8) =
                *(const f16x8*)(A + (size_t)(row0 + sr0) * K + k0 + sg0 * 8);
            *(f16x8*)(As + sr1 * TPAD + sg1 * 8) =
                *(const f16x8*)(A + (size_t)(row0 + sr1) * K + k0 + sg1 * 8);
            *(f16x8*)(Bs + sr0 * TPAD + sg0 * 8) =
                *(const f16x8*)(W + (size_t)(col0 + sr0) * K + k0 + sg0 * 8);
            *(f16x8*)(Bs + sr1 * TPAD + sg1 * 8) =
                *(const f16x8*)(W + (size_t)(col0 + sr1) * K + k0 + sg1 * 8);
            if (KM == 1) {
                *(f16x8*)(As2 + sr0 * TPAD + sg0 * 8) =
                    *(const f16x8*)(A2 + (size_t)(row0 + sr0) * K + k0 + sg0 * 8);
                *(f16x8*)(As2 + sr1 * TPAD + sg1 * 8) =
                    *(const f16x8*)(A2 + (size_t)(row0 + sr1) * K + k0 + sg1 * 8);
            }
            if (KM >= 1) {
                *(f16x8*)(Bs2 + sr0 * TPAD + sg0 * 8) =
                    *(const f16x8*)(W2 + (size_t)(col0 + sr0) * K + k0 + sg0 * 8);
                *(f16x8*)(Bs2 + sr1 * TPAD + sg1 * 8) =
                    *(const f16x8*)(W2 + (size_t)(col0 + sr1) * K + k0 + sg1 * 8);
            }
        }
        __syncthreads();

        f16x8 aF[4], bF[4];
#pragma unroll
        for (int mi = 0; mi < 4; ++mi)
            aF[mi] = *(const f16x8*)(abase + mi * 16 * TPAD);
#pragma unroll
        for (int ni = 0; ni < 4; ++ni)
            bF[ni] = *(const f16x8*)(bbase + ni * 16 * TPAD);
#pragma unroll
        for (int mi = 0; mi < 4; ++mi)
#pragma unroll
            for (int ni = 0; ni < 4; ++ni)
                acc[mi][ni] = __builtin_amdgcn_mfma_f32_16x16x32_f16(
                    aF[mi], bF[ni], acc[mi][ni], 0, 0, 0);

        if (KM == 1) {
            f16x8 a2F[4], b2F[4];
#pragma unroll
            for (int mi = 0; mi < 4; ++mi)
                a2F[mi] = *(const f16x8*)(abase + TILE_ELE + mi * 16 * TPAD);
#pragma unroll
            for (int ni = 0; ni < 4; ++ni)
                b2F[ni] = *(const f16x8*)(bbase + TILE_ELE + ni * 16 * TPAD); // FIXED: was 2*TILE_ELE (OOB)
#pragma unroll
            for (int mi = 0; mi < 4; ++mi)
#pragma unroll
                for (int ni = 0; ni < 4; ++ni)
                    acc[mi][ni] = __builtin_amdgcn_mfma_f32_16x16x32_f16(
                        a2F[mi], b2F[ni], acc[mi][ni], 0, 0, 0);
        }
        if (KM == 2) {
            f16x8 b2F[4];
#pragma unroll
            for (int ni = 0; ni < 4; ++ni)
                b2F[ni] = *(const f16x8*)(bbase + TILE_ELE + ni * 16 * TPAD);
#pragma unroll
            for (int mi = 0; mi < 4; ++mi)
#pragma unroll
                for (int ni = 0; ni < 4; ++ni)
                    acc2[mi][ni] = __builtin_amdgcn_mfma_f32_16x16x32_f16(
                        aF[mi], b2F[ni], acc2[mi][ni], 0, 0, 0);
        }
    }

    // ---------------- epilogue ----------------
    float* Cf32 = (float*)Cout;
    f16*   Cf16 = (f16*)Cout;
#pragma unroll
    for (int mi = 0; mi < 4; ++mi) {
#pragma unroll
        for (int ni = 0; ni < 4; ++ni) {
            const int col   = col0 + wc * 64 + ni * 16 + lc;
            const int rbase = row0 + wr * 64 + mi * 16 + lr * 4;
            const f32x4 v = acc[mi][ni];
            if (KM == 0) {
                const float bv = bias ? bias[col] : 0.f;
#pragma unroll
                for (int r = 0; r < 4; ++r) {
                    const float o = v[r] + bv;
                    const size_t idx = (size_t)(rbase + r) * N + col;
                    if (OUTF16) Cf16[idx] = (f16)o; else Cf32[idx] = o;
                }
            } else if (KM == 1) {
                const float dv = DV[col];
#pragma unroll
                for (int r = 0; r < 4; ++r) {
                    const size_t idx = (size_t)(rbase + r) * N + col;
                    const float o = gelu_tanh_f(v[r] + dv * (float)EX[idx]);
                    if (OUTF16) Cf16[idx] = (f16)o; else Cf32[idx] = o;
                }
            } else {
                const float b1 = bias[col], b2 = bias2[col];
                const f32x4 v2 = acc2[mi][ni];
#pragma unroll
                for (int r = 0; r < 4; ++r) {
                    const size_t idx = (size_t)(rbase + r) * N + col;
                    const float o = (float)EX[idx] + (v[r] + b1) * sigmoid_f(v2[r] + b2);
                    if (OUTF16) Cf16[idx] = (f16)o; else Cf32[idx] = o;
                }
            }
        }
    }
}

// ---------------- LayerNorm (rows of 512, f16 in/out) ----------------
__global__ __launch_bounds__(256) void layernorm_f16(
    const f16* __restrict__ X, const float* __restrict__ g,
    const float* __restrict__ b, f16* __restrict__ Y)
{
    const int lane = threadIdx.x & 63;
    const int w    = threadIdx.x >> 6;
    const int row  = blockIdx.x * 4 + w;
    const size_t base = (size_t)row * Dm + lane * 8;

    const f16x8 v = *(const f16x8*)(X + base);
    float x[8];
    float s = 0.f, q = 0.f;
#pragma unroll
    for (int i = 0; i < 8; ++i) {
        x[i] = (float)v[i];
        s += x[i]; q += x[i] * x[i];
    }
#pragma unroll
    for (int off = 32; off > 0; off >>= 1) {
        s += __shfl_xor(s, off);
        q += __shfl_xor(q, off);
    }
    const float mu  = s * (1.f / 512.f);
    const float var = q * (1.f / 512.f) - mu * mu;
    const float rs  = rsqrtf(var + 1e-5f);

    const float4 g0 = *(const float4*)(g + lane * 8);
    const float4 g1 = *(const float4*)(g + lane * 8 + 4);
    const float4 b0 = *(const float4*)(b + lane * 8);
    const float4 b1 = *(const float4*)(b + lane * 8 + 4);
    const float gg[8] = {g0.x, g0.y, g0.z, g0.w, g1.x, g1.y, g1.z, g1.w};
    const float bb[8] = {b0.x, b0.y, b0.z, b0.w, b1.x, b1.y, b1.z, b1.w};
    f16x8 o;
#pragma unroll
    for (int i = 0; i < 8; ++i)
        o[i] = (f16)((x[i] - mu) * rs * gg[i] + bb[i]);
    *(f16x8*)(Y + base) = o;
}

// ---------------- scan constants ----------------
__global__ void consts_k(const float* __restrict__ A_diag,
                         const float* __restrict__ log_steps,
                         float* __restrict__ cst)
{
    const int n = threadIdx.x;
    const float a   = fmaxf(A_diag[n], 0.f);
    const float dt  = 1.f / (1.f + expf(-log_steps[n]));
    const float d2a = dt * dt * a;
    const float S   = 1.f / (1.f + d2a);
    const float m11 = 1.f - d2a * S;
    const float m12 = -dt * a * S;
    const float m21 = dt * S;
    const float m22 = S;
    cst[n]            = m11;
    cst[Dm + n]       = m12;
    cst[2 * Dm + n]   = m21;
    cst[3 * Dm + n]   = m22;
    cst[4 * Dm + n]   = m11 * dt;
    cst[5 * Dm + n]   = m21 * dt;
}

// ---------------- scan phase 1 ----------------
__global__ __launch_bounds__(512) void scan_phase1(
    const float* __restrict__ bur, const float* __restrict__ bui,
    const float* __restrict__ cst, float* __restrict__ S1)
{
    const int n = threadIdx.x;
    const int c = blockIdx.x & (NC - 1);
    const int b = blockIdx.x >> 5;
    const float m11 = cst[n],          m12 = cst[Dm + n];
    const float m21 = cst[2 * Dm + n], m22 = cst[3 * Dm + n];
    const float c1  = cst[4 * Dm + n], c2  = cst[5 * Dm + n];

    float zr = 0.f, xr = 0.f, zi = 0.f, xi = 0.f;
    const size_t base = ((size_t)b * Ll + (size_t)c * CL) * Dm + n;
#pragma unroll 4
    for (int t = 0; t < CL; ++t) {
        const float br = bur[base + (size_t)t * Dm];
        const float bi = bui[base + (size_t)t * Dm];
        const float zrn = fmaf(m11, zr, fmaf(m12, xr, c1 * br));
        const float xrn = fmaf(m21, zr, fmaf(m22, xr, c2 * br));
        const float zin = fmaf(m11, zi, fmaf(m12, xi, c1 * bi));
        const float xin = fmaf(m21, zi, fmaf(m22, xi, c2 * bi));
        zr = zrn; xr = xrn; zi = zin; xi = xin;
    }
    const int idx = blockIdx.x * Dm + n;
    S1[idx]            = zr;
    S1[SZ1 + idx]      = xr;
    S1[2 * SZ1 + idx]  = zi;
    S1[3 * SZ1 + idx]  = xi;
}

// ---------------- scan phase 2 ----------------
__global__ __launch_bounds__(256) void scan_phase2(
    const float* __restrict__ S1, const float* __restrict__ cst,
    float* __restrict__ G)
{
    const int gidx = blockIdx.x * 256 + threadIdx.x; // 0..4095
    const int n = gidx & (Dm - 1);
    const int b = gidx >> 9;
    const float m11 = cst[n],          m12 = cst[Dm + n];
    const float m21 = cst[2 * Dm + n], m22 = cst[3 * Dm + n];

    float p11 = 1.f, p12 = 0.f, p21 = 0.f, p22 = 1.f;
    for (int i = 0; i < CL; ++i) {
        const float q11 = m11 * p11 + m12 * p21;
        const float q12 = m11 * p12 + m12 * p22;
        const float q21 = m21 * p11 + m22 * p21;
        const float q22 = m21 * p12 + m22 * p22;
        p11 = q11; p12 = q12; p21 = q21; p22 = q22;
    }

    float gzr = 0.f, gxr = 0.f, gzi = 0.f, gxi = 0.f;
    for (int c = 0; c < NC; ++c) {
        const int idx = (b * NC + c) * Dm + n;
        G[idx]           = gzr;
        G[SZ1 + idx]     = gxr;
        G[2 * SZ1 + idx] = gzi;
        G[3 * SZ1 + idx] = gxi;
        const float szr = S1[idx],           sxr = S1[SZ1 + idx];
        const float szi = S1[2 * SZ1 + idx], sxi = S1[3 * SZ1 + idx];
        const float t1 = p11 * gzr + p12 * gxr + szr;
        const float t2 = p21 * gzr + p22 * gxr + sxr;
        const float t3 = p11 * gzi + p12 * gxi + szi;
        const float t4 = p21 * gzi + p22 * gxi + sxi;
        gzr = t1; gxr = t2; gzi = t3; gxi = t4;
    }
}

// ---------------- scan phase 3: fp32 state, f16 xs out (imag negated) ----------------
__global__ __launch_bounds__(512) void scan_phase3(
    const float* __restrict__ bur, const float* __restrict__ bui,
    const float* __restrict__ cst, const float* __restrict__ G,
    f16* __restrict__ xrf, f16* __restrict__ xif)
{
    const int n = threadIdx.x;
    const int c = blockIdx.x & (NC - 1);
    const int b = blockIdx.x >> 5;
    const float m11 = cst[n],          m12 = cst[Dm + n];
    const float m21 = cst[2 * Dm + n], m22 = cst[3 * Dm + n];
    const float c1  = cst[4 * Dm + n], c2  = cst[5 * Dm + n];

    const int sidx = blockIdx.x * Dm + n;
    float zr = G[sidx];
    float xr = G[SZ1 + sidx];
    float zi = G[2 * SZ1 + sidx];
    float xi = G[3 * SZ1 + sidx];

    const size_t base = ((size_t)b * Ll + (size_t)c * CL) * Dm + n;
#pragma unroll 4
    for (int t = 0; t < CL; ++t) {
        const float br = bur[base + (size_t)t * Dm];
        const float bi = bui[base + (size_t)t * Dm];
        const float zrn = fmaf(m11, zr, fmaf(m12, xr, c1 * br));
        const float xrn = fmaf(m21, zr, fmaf(m22, xr, c2 * br));
        const float zin = fmaf(m11, zi, fmaf(m12, xi, c1 * bi));
        const float xin = fmaf(m21, zi, fmaf(m22, xi, c2 * bi));
        zr = zrn; xr = xrn; zi = zin; xi = xin;
        xrf[base + (size_t)t * Dm] = (f16)xr;
        xif[base + (size_t)t * Dm] = (f16)(-xi);   // pre-negated for fused C-proj
    }
}

// ---------------- launch ----------------
extern "C" void kernel_launch(void* const* d_in, const int* in_sizes, int n_in,
                              void* d_out, int out_size, void* d_ws, size_t ws_size,
                              hipStream_t stream)
{
    const float* x         = (const float*)d_in[0];
    const float* W_in      = (const float*)d_in[1];
    const float* b_in      = (const float*)d_in[2];
    const float* W_enc     = (const float*)d_in[3];
    const float* b_enc     = (const float*)d_in[4];
    const float* ln_g      = (const float*)d_in[5];
    const float* ln_b      = (const float*)d_in[6];
    const float* A_diag    = (const float*)d_in[7];
    const float* log_steps = (const float*)d_in[8];
    const float* B_re      = (const float*)d_in[9];
    const float* B_im      = (const float*)d_in[10];
    const float* C_re      = (const float*)d_in[11];
    const float* C_im      = (const float*)d_in[12];
    const float* Dv        = (const float*)d_in[13];
    const float* glu_w1    = (const float*)d_in[14];
    const float* glu_b1    = (const float*)d_in[15];
    const float* glu_w2    = (const float*)d_in[16];
    const float* glu_b2    = (const float*)d_in[17];
    const float* W_dec     = (const float*)d_in[18];
    const float* b_dec     = (const float*)d_in[19];
    const float* W_out     = (const float*)d_in[20];
    const float* b_out     = (const float*)d_in[21];

    char* ws = (char*)d_ws;
    const size_t MB = 1 << 20;
    f16*   F0  = (f16*)(ws);             // h1f, later xs_re f16
    f16*   F1  = (f16*)(ws + 16 * MB);   // xs_im f16 (negated)
    f16*   F2  = (f16*)(ws + 32 * MB);   // skipf, later h3f
    f16*   F3  = (f16*)(ws + 48 * MB);   // hnf, later h2f
    float* BuR = (float*)(ws + 64 * MB); // fp32 Bu real (32MB)
    float* BuI = (float*)(ws + 96 * MB); // fp32 Bu imag (32MB)
    f16*   GF  = (f16*)(ws + 64 * MB);   // g (aliases BuR, dead by then)
    f16*   XF  = (f16*)(ws + 128 * MB);  // x in f16 (4MB)
    float* S1  = (float*)(ws + 132 * MB);
    float* G   = (float*)(ws + 134 * MB);
    float* cst = (float*)(ws + 136 * MB);
    f16*   wbuf = (f16*)(ws + 137 * MB);
    f16* WFIN  = wbuf;                 // 65536
    f16* WFENC = WFIN  + 65536;        // 262144
    f16* BFRE  = WFENC + 262144;
    f16* BFIM  = BFRE  + 262144;
    f16* CFRE  = BFIM  + 262144;
    f16* CFIM  = CFRE  + 262144;
    f16* W1F   = CFIM  + 262144;
    f16* W2F   = W1F   + 262144;
    f16* WFDEC = W2F   + 262144;
    f16* WFOUT = WFDEC + 262144;       // 65536

    CvtJobs jobs;
    jobs.j[0]  = {x,      XF,    Mrows * Hin};
    jobs.j[1]  = {W_in,   WFIN,  Dm * Hin};
    jobs.j[2]  = {W_enc,  WFENC, Dm * Dm};
    jobs.j[3]  = {B_re,   BFRE,  Dm * Dm};
    jobs.j[4]  = {B_im,   BFIM,  Dm * Dm};
    jobs.j[5]  = {C_re,   CFRE,  Dm * Dm};
    jobs.j[6]  = {C_im,   CFIM,  Dm * Dm};
    jobs.j[7]  = {glu_w1, W1F,   Dm * Dm};
    jobs.j[8]  = {glu_w2, W2F,   Dm * Dm};
    jobs.j[9]  = {W_dec,  WFDEC, Dm * Dm};
    jobs.j[10] = {W_out,  WFOUT, Hin * Dm};

    convert_k<<<dim3((Mrows * Hin) / 1024, 11), 256, 0, stream>>>(jobs);
    consts_k<<<1, Dm, 0, stream>>>(A_diag, log_steps, cst);

    dim3 blk(256);
    dim3 g512(Mrows / 128, Dm / 128);   // (128, 4)
    dim3 g128(Mrows / 128, Hin / 128);  // (128, 1)

    // h1f = x @ W_in^T + b_in
    gemm_mfma<0, 1><<<g512, blk, 0, stream>>>(XF, nullptr, WFIN, nullptr, b_in, nullptr,
                                              nullptr, nullptr, F0, Mrows, Dm, Hin);
    // skipf = h1f @ W_enc^T + b_enc
    gemm_mfma<0, 1><<<g512, blk, 0, stream>>>(F0, nullptr, WFENC, nullptr, b_enc, nullptr,
                                              nullptr, nullptr, F2, Mrows, Dm, Dm);
    // hnf = layernorm(skipf)
    layernorm_f16<<<Mrows / 4, 256, 0, stream>>>(F2, ln_g, ln_b, F3);
    // Bu (fp32 for the scan)
    gemm_mfma<0, 0><<<g512, blk, 0, stream>>>(F3, nullptr, BFRE, nullptr, nullptr, nullptr,
                                              nullptr, nullptr, BuR, Mrows, Dm, Dm);
    gemm_mfma<0, 0><<<g512, blk, 0, stream>>>(F3, nullptr, BFIM, nullptr, nullptr, nullptr,
                                              nullptr, nullptr, BuI, Mrows, Dm, Dm);
    // LinOSS scan (fp32 state), xs out as f16 (imag negated)
    scan_phase1<<<Bb * NC, 512, 0, stream>>>(BuR, BuI, cst, S1);
    scan_phase2<<<(Bb * Dm) / 256, 256, 0, stream>>>(S1, cst, G);
    scan_phase3<<<Bb * NC, 512, 0, stream>>>(BuR, BuI, cst, G, F0, F1);
    // g = gelu(xs_re@C_re^T - xs_im@C_im^T + D*hn)
    gemm_mfma<1, 1><<<g512, blk, 0, stream>>>(F0, F1, CFRE, CFIM, nullptr, nullptr,
                                              F3, Dv, GF, Mrows, Dm, Dm);
    // h2f = skip + (g@w1^T+b1)*sigmoid(g@w2^T+b2)
    gemm_mfma<2, 1><<<g512, blk, 0, stream>>>(GF, nullptr, W1F, W2F, glu_b1, glu_b2,
                                              F2, nullptr, F3, Mrows, Dm, Dm);
    // h3f = h2f @ W_dec^T + b_dec
    gemm_mfma<0, 1><<<g512, blk, 0, stream>>>(F3, nullptr, WFDEC, nullptr, b_dec, nullptr,
                                              nullptr, nullptr, F2, Mrows, Dm, Dm);
    // out = h3f @ W_out^T + b_out  (fp32)
    gemm_mfma<0, 0><<<g128, blk, 0, stream>>>(F2, nullptr, WFOUT, nullptr, b_out, nullptr,
                                              nullptr, nullptr, (float*)d_out, Mrows, Hin, Dm);
}

// Round 4
// 328.133 us; speedup vs baseline: 3.4177x; 1.0764x over previous
//
#include <hip/hip_runtime.h>
#include <cstddef>
#include <cstdint>
#include <math.h>

typedef _Float16 f16;
typedef f16 f16x8 __attribute__((ext_vector_type(8)));
typedef f16 f16x4 __attribute__((ext_vector_type(4)));
typedef float f32x4 __attribute__((ext_vector_type(4)));

// ---------------- problem constants ----------------
constexpr int Bb   = 8;
constexpr int Ll   = 2048;
constexpr int Hin  = 128;
constexpr int Dm   = 512;
constexpr int Mrows = Bb * Ll;          // 16384
constexpr int NC   = 32;                // scan chunks per sequence
constexpr int CL   = Ll / NC;           // 64 timesteps per chunk
constexpr int SZ1  = Bb * NC * Dm;      // 131072 per state component

constexpr int TILE_ELE = 128 * 64;      // one 128x64 f16 tile = 8192 elems = 16 KB

// ---------------- device math helpers ----------------
static __device__ __forceinline__ float sigmoid_f(float x) {
    return 1.f / (1.f + expf(-x));
}
static __device__ __forceinline__ float gelu_tanh_f(float x) {
    float x3 = x * x * x;
    float t  = tanhf(0.7978845608028654f * (x + 0.044715f * x3));
    return 0.5f * x * (1.f + t);
}

// async global->LDS, 16 bytes per lane (linear LDS dest: wave base + lane*16)
static __device__ __forceinline__ void gld16(const f16* g, f16* l) {
    __builtin_amdgcn_global_load_lds(
        (const __attribute__((address_space(1))) void*)g,
        (__attribute__((address_space(3))) void*)l, 16, 0, 0);
}

// ---------------- weight/x fp32 -> f16 conversion ----------------
struct CvtJob { const float* s; f16* d; int n; };
struct CvtJobs { CvtJob j[11]; };

__global__ __launch_bounds__(256) void convert_k(CvtJobs jobs) {
    const CvtJob jb = jobs.j[blockIdx.y];
    const int i = (blockIdx.x * 256 + threadIdx.x) * 4;
    if (i >= jb.n) return;
    const float4 v = *(const float4*)(jb.s + i);
    f16x4 o;
    o.x = (f16)v.x; o.y = (f16)v.y; o.z = (f16)v.z; o.w = (f16)v.w;
    *(f16x4*)(jb.d + i) = o;
}

// ---------------- fused MFMA GEMM (128x128 tile, BK=64, gload_lds + T2 swizzle) ----
// C[M,N] = epilogue( A[M,K] @ W[N,K]^T )
// KM=0: C = A@W^T + bias (bias may be null)
// KM=1: C = gelu( A@W^T + A2@W2^T + DV[col]*EX )   (A2 pre-negated imag part)
// KM=2: C = EX + (A@W^T + bias)*sigmoid(A@W2^T + bias2)
// KM=3: C = A@W^T (fp32), C2 = A@W2^T (fp32)        (dual Bu projection)
template <int KM, int OUTF16>
__global__ __launch_bounds__(256) void gemm_mfma(
    const f16* __restrict__ A, const f16* __restrict__ A2,
    const f16* __restrict__ W, const f16* __restrict__ W2,
    const float* __restrict__ bias, const float* __restrict__ bias2,
    const f16* __restrict__ EX, const float* __restrict__ DV,
    void* __restrict__ Cout, void* __restrict__ Cout2, int M, int N, int K)
{
    constexpr int NTILE = (KM == 1) ? 4 : (KM == 0 ? 2 : 3);
    __shared__ f16 smem[NTILE * TILE_ELE];
    f16* As  = smem;
    f16* As2 = (KM == 1) ? smem + TILE_ELE : nullptr;
    f16* Bs  = smem + ((KM == 1) ? 2 : 1) * TILE_ELE;
    f16* Bs2 = (KM >= 1) ? Bs + TILE_ELE : nullptr;

    const int tid = threadIdx.x;
    const int l   = tid & 63;
    const int wid = tid >> 6;       // 0..3
    const int wr  = wid >> 1;       // row half
    const int wc  = wid & 1;        // col half
    const int lc  = l & 15;
    const int lr  = l >> 4;         // k-slot / out row group
    const int row0 = blockIdx.x * 128;
    const int col0 = blockIdx.y * 128;

    // T2 swizzle: within-row byte offset XOR'd with ((row&7)<<4); row&7 == l&7 for frags
    const int swz  = (l & 7) << 4;
    const int off0 = (((lr * 16)      ^ swz) >> 1); // f16 elems, k-step 0
    const int off1 = (((64 + lr * 16) ^ swz) >> 1); // k-step 1

    f32x4 acc[4][4];
    f32x4 acc2[(KM >= 2) ? 4 : 1][(KM >= 2) ? 4 : 1];
#pragma unroll
    for (int i = 0; i < 4; ++i)
#pragma unroll
        for (int j = 0; j < 4; ++j) {
            acc[i][j] = (f32x4){0.f, 0.f, 0.f, 0.f};
            if (KM >= 2) acc2[i][j] = (f32x4){0.f, 0.f, 0.f, 0.f};
        }

    // staging: 1024 16B-chunks per tile; chunk -> LDS linear, global src pre-swizzled
#define STAGE(LDS, GSRC)                                                     \
    {                                                                        \
        _Pragma("unroll")                                                    \
        for (int c = 0; c < 4; ++c) {                                        \
            const int chunk = c * 256 + tid;                                 \
            const int row   = chunk >> 3;                                    \
            const int kb    = ((chunk & 7) << 4) ^ ((row & 7) << 4);         \
            gld16(GSRC + (size_t)row * K + (kb >> 1), LDS + chunk * 8);      \
        }                                                                    \
    }

    for (int k0 = 0; k0 < K; k0 += 64) {
        __syncthreads();
        STAGE(As, A + (size_t)row0 * K + k0);
        STAGE(Bs, W + (size_t)col0 * K + k0);
        if (KM == 1) STAGE(As2, A2 + (size_t)row0 * K + k0);
        if (KM >= 1) STAGE(Bs2, W2 + (size_t)col0 * K + k0);
        __syncthreads();   // compiler drains vmcnt before barrier

#pragma unroll
        for (int ks = 0; ks < 2; ++ks) {
            const int off = ks ? off1 : off0;
            f16x8 aF[4], bF[4];
#pragma unroll
            for (int mi = 0; mi < 4; ++mi)
                aF[mi] = *(const f16x8*)(As + (wr * 64 + mi * 16 + lc) * 64 + off);
#pragma unroll
            for (int ni = 0; ni < 4; ++ni)
                bF[ni] = *(const f16x8*)(Bs + (wc * 64 + ni * 16 + lc) * 64 + off);
#pragma unroll
            for (int mi = 0; mi < 4; ++mi)
#pragma unroll
                for (int ni = 0; ni < 4; ++ni)
                    acc[mi][ni] = __builtin_amdgcn_mfma_f32_16x16x32_f16(
                        aF[mi], bF[ni], acc[mi][ni], 0, 0, 0);

            if (KM == 1) {
                f16x8 a2F[4], b2F[4];
#pragma unroll
                for (int mi = 0; mi < 4; ++mi)
                    a2F[mi] = *(const f16x8*)(As2 + (wr * 64 + mi * 16 + lc) * 64 + off);
#pragma unroll
                for (int ni = 0; ni < 4; ++ni)
                    b2F[ni] = *(const f16x8*)(Bs2 + (wc * 64 + ni * 16 + lc) * 64 + off);
#pragma unroll
                for (int mi = 0; mi < 4; ++mi)
#pragma unroll
                    for (int ni = 0; ni < 4; ++ni)
                        acc[mi][ni] = __builtin_amdgcn_mfma_f32_16x16x32_f16(
                            a2F[mi], b2F[ni], acc[mi][ni], 0, 0, 0);
            }
            if (KM >= 2) {
                f16x8 b2F[4];
#pragma unroll
                for (int ni = 0; ni < 4; ++ni)
                    b2F[ni] = *(const f16x8*)(Bs2 + (wc * 64 + ni * 16 + lc) * 64 + off);
#pragma unroll
                for (int mi = 0; mi < 4; ++mi)
#pragma unroll
                    for (int ni = 0; ni < 4; ++ni)
                        acc2[mi][ni] = __builtin_amdgcn_mfma_f32_16x16x32_f16(
                            aF[mi], b2F[ni], acc2[mi][ni], 0, 0, 0);
            }
        }
    }
#undef STAGE

    // ---------------- epilogue ----------------
    float* Cf32  = (float*)Cout;
    f16*   Cf16  = (f16*)Cout;
    float* C2f32 = (float*)Cout2;
#pragma unroll
    for (int mi = 0; mi < 4; ++mi) {
#pragma unroll
        for (int ni = 0; ni < 4; ++ni) {
            const int col   = col0 + wc * 64 + ni * 16 + lc;
            const int rbase = row0 + wr * 64 + mi * 16 + lr * 4;
            const f32x4 v = acc[mi][ni];
            if (KM == 0) {
                const float bv = bias ? bias[col] : 0.f;
#pragma unroll
                for (int r = 0; r < 4; ++r) {
                    const float o = v[r] + bv;
                    const size_t idx = (size_t)(rbase + r) * N + col;
                    if (OUTF16) Cf16[idx] = (f16)o; else Cf32[idx] = o;
                }
            } else if (KM == 1) {
                const float dv = DV[col];
#pragma unroll
                for (int r = 0; r < 4; ++r) {
                    const size_t idx = (size_t)(rbase + r) * N + col;
                    const float o = gelu_tanh_f(v[r] + dv * (float)EX[idx]);
                    if (OUTF16) Cf16[idx] = (f16)o; else Cf32[idx] = o;
                }
            } else if (KM == 2) {
                const float b1 = bias[col], b2 = bias2[col];
                const f32x4 v2 = acc2[mi][ni];
#pragma unroll
                for (int r = 0; r < 4; ++r) {
                    const size_t idx = (size_t)(rbase + r) * N + col;
                    const float o = (float)EX[idx] + (v[r] + b1) * sigmoid_f(v2[r] + b2);
                    if (OUTF16) Cf16[idx] = (f16)o; else Cf32[idx] = o;
                }
            } else { // KM == 3: dual fp32 outputs
                const f32x4 v2 = acc2[mi][ni];
#pragma unroll
                for (int r = 0; r < 4; ++r) {
                    const size_t idx = (size_t)(rbase + r) * N + col;
                    Cf32[idx]  = v[r];
                    C2f32[idx] = v2[r];
                }
            }
        }
    }
}

// ---------------- LayerNorm (rows of 512, f16 in/out) ----------------
__global__ __launch_bounds__(256) void layernorm_f16(
    const f16* __restrict__ X, const float* __restrict__ g,
    const float* __restrict__ b, f16* __restrict__ Y)
{
    const int lane = threadIdx.x & 63;
    const int w    = threadIdx.x >> 6;
    const int row  = blockIdx.x * 4 + w;
    const size_t base = (size_t)row * Dm + lane * 8;

    const f16x8 v = *(const f16x8*)(X + base);
    float x[8];
    float s = 0.f, q = 0.f;
#pragma unroll
    for (int i = 0; i < 8; ++i) {
        x[i] = (float)v[i];
        s += x[i]; q += x[i] * x[i];
    }
#pragma unroll
    for (int off = 32; off > 0; off >>= 1) {
        s += __shfl_xor(s, off);
        q += __shfl_xor(q, off);
    }
    const float mu  = s * (1.f / 512.f);
    const float var = q * (1.f / 512.f) - mu * mu;
    const float rs  = rsqrtf(var + 1e-5f);

    const float4 g0 = *(const float4*)(g + lane * 8);
    const float4 g1 = *(const float4*)(g + lane * 8 + 4);
    const float4 b0 = *(const float4*)(b + lane * 8);
    const float4 b1 = *(const float4*)(b + lane * 8 + 4);
    const float gg[8] = {g0.x, g0.y, g0.z, g0.w, g1.x, g1.y, g1.z, g1.w};
    const float bb[8] = {b0.x, b0.y, b0.z, b0.w, b1.x, b1.y, b1.z, b1.w};
    f16x8 o;
#pragma unroll
    for (int i = 0; i < 8; ++i)
        o[i] = (f16)((x[i] - mu) * rs * gg[i] + bb[i]);
    *(f16x8*)(Y + base) = o;
}

// ---------------- scan constants ----------------
__global__ void consts_k(const float* __restrict__ A_diag,
                         const float* __restrict__ log_steps,
                         float* __restrict__ cst)
{
    const int n = threadIdx.x;
    const float a   = fmaxf(A_diag[n], 0.f);
    const float dt  = 1.f / (1.f + expf(-log_steps[n]));
    const float d2a = dt * dt * a;
    const float S   = 1.f / (1.f + d2a);
    const float m11 = 1.f - d2a * S;
    const float m12 = -dt * a * S;
    const float m21 = dt * S;
    const float m22 = S;
    cst[n]            = m11;
    cst[Dm + n]       = m12;
    cst[2 * Dm + n]   = m21;
    cst[3 * Dm + n]   = m22;
    cst[4 * Dm + n]   = m11 * dt;
    cst[5 * Dm + n]   = m21 * dt;
}

// ---------------- scan phase 1 ----------------
__global__ __launch_bounds__(512) void scan_phase1(
    const float* __restrict__ bur, const float* __restrict__ bui,
    const float* __restrict__ cst, float* __restrict__ S1)
{
    const int n = threadIdx.x;
    const int c = blockIdx.x & (NC - 1);
    const int b = blockIdx.x >> 5;
    const float m11 = cst[n],          m12 = cst[Dm + n];
    const float m21 = cst[2 * Dm + n], m22 = cst[3 * Dm + n];
    const float c1  = cst[4 * Dm + n], c2  = cst[5 * Dm + n];

    float zr = 0.f, xr = 0.f, zi = 0.f, xi = 0.f;
    const size_t base = ((size_t)b * Ll + (size_t)c * CL) * Dm + n;
#pragma unroll 4
    for (int t = 0; t < CL; ++t) {
        const float br = bur[base + (size_t)t * Dm];
        const float bi = bui[base + (size_t)t * Dm];
        const float zrn = fmaf(m11, zr, fmaf(m12, xr, c1 * br));
        const float xrn = fmaf(m21, zr, fmaf(m22, xr, c2 * br));
        const float zin = fmaf(m11, zi, fmaf(m12, xi, c1 * bi));
        const float xin = fmaf(m21, zi, fmaf(m22, xi, c2 * bi));
        zr = zrn; xr = xrn; zi = zin; xi = xin;
    }
    const int idx = blockIdx.x * Dm + n;
    S1[idx]            = zr;
    S1[SZ1 + idx]      = xr;
    S1[2 * SZ1 + idx]  = zi;
    S1[3 * SZ1 + idx]  = xi;
}

// ---------------- scan phase 2 ----------------
__global__ __launch_bounds__(256) void scan_phase2(
    const float* __restrict__ S1, const float* __restrict__ cst,
    float* __restrict__ G)
{
    const int gidx = blockIdx.x * 256 + threadIdx.x; // 0..4095
    const int n = gidx & (Dm - 1);
    const int b = gidx >> 9;
    const float m11 = cst[n],          m12 = cst[Dm + n];
    const float m21 = cst[2 * Dm + n], m22 = cst[3 * Dm + n];

    float p11 = 1.f, p12 = 0.f, p21 = 0.f, p22 = 1.f;
    for (int i = 0; i < CL; ++i) {
        const float q11 = m11 * p11 + m12 * p21;
        const float q12 = m11 * p12 + m12 * p22;
        const float q21 = m21 * p11 + m22 * p21;
        const float q22 = m21 * p12 + m22 * p22;
        p11 = q11; p12 = q12; p21 = q21; p22 = q22;
    }

    float gzr = 0.f, gxr = 0.f, gzi = 0.f, gxi = 0.f;
    for (int c = 0; c < NC; ++c) {
        const int idx = (b * NC + c) * Dm + n;
        G[idx]           = gzr;
        G[SZ1 + idx]     = gxr;
        G[2 * SZ1 + idx] = gzi;
        G[3 * SZ1 + idx] = gxi;
        const float szr = S1[idx],           sxr = S1[SZ1 + idx];
        const float szi = S1[2 * SZ1 + idx], sxi = S1[3 * SZ1 + idx];
        const float t1 = p11 * gzr + p12 * gxr + szr;
        const float t2 = p21 * gzr + p22 * gxr + sxr;
        const float t3 = p11 * gzi + p12 * gxi + szi;
        const float t4 = p21 * gzi + p22 * gxi + sxi;
        gzr = t1; gxr = t2; gzi = t3; gxi = t4;
    }
}

// ---------------- scan phase 3: fp32 state, f16 xs out (imag negated) ----------------
__global__ __launch_bounds__(512) void scan_phase3(
    const float* __restrict__ bur, const float* __restrict__ bui,
    const float* __restrict__ cst, const float* __restrict__ G,
    f16* __restrict__ xrf, f16* __restrict__ xif)
{
    const int n = threadIdx.x;
    const int c = blockIdx.x & (NC - 1);
    const int b = blockIdx.x >> 5;
    const float m11 = cst[n],          m12 = cst[Dm + n];
    const float m21 = cst[2 * Dm + n], m22 = cst[3 * Dm + n];
    const float c1  = cst[4 * Dm + n], c2  = cst[5 * Dm + n];

    const int sidx = blockIdx.x * Dm + n;
    float zr = G[sidx];
    float xr = G[SZ1 + sidx];
    float zi = G[2 * SZ1 + sidx];
    float xi = G[3 * SZ1 + sidx];

    const size_t base = ((size_t)b * Ll + (size_t)c * CL) * Dm + n;
#pragma unroll 4
    for (int t = 0; t < CL; ++t) {
        const float br = bur[base + (size_t)t * Dm];
        const float bi = bui[base + (size_t)t * Dm];
        const float zrn = fmaf(m11, zr, fmaf(m12, xr, c1 * br));
        const float xrn = fmaf(m21, zr, fmaf(m22, xr, c2 * br));
        const float zin = fmaf(m11, zi, fmaf(m12, xi, c1 * bi));
        const float xin = fmaf(m21, zi, fmaf(m22, xi, c2 * bi));
        zr = zrn; xr = xrn; zi = zin; xi = xin;
        xrf[base + (size_t)t * Dm] = (f16)xr;
        xif[base + (size_t)t * Dm] = (f16)(-xi);   // pre-negated for fused C-proj
    }
}

// ---------------- launch ----------------
extern "C" void kernel_launch(void* const* d_in, const int* in_sizes, int n_in,
                              void* d_out, int out_size, void* d_ws, size_t ws_size,
                              hipStream_t stream)
{
    const float* x         = (const float*)d_in[0];
    const float* W_in      = (const float*)d_in[1];
    const float* b_in      = (const float*)d_in[2];
    const float* W_enc     = (const float*)d_in[3];
    const float* b_enc     = (const float*)d_in[4];
    const float* ln_g      = (const float*)d_in[5];
    const float* ln_b      = (const float*)d_in[6];
    const float* A_diag    = (const float*)d_in[7];
    const float* log_steps = (const float*)d_in[8];
    const float* B_re      = (const float*)d_in[9];
    const float* B_im      = (const float*)d_in[10];
    const float* C_re      = (const float*)d_in[11];
    const float* C_im      = (const float*)d_in[12];
    const float* Dv        = (const float*)d_in[13];
    const float* glu_w1    = (const float*)d_in[14];
    const float* glu_b1    = (const float*)d_in[15];
    const float* glu_w2    = (const float*)d_in[16];
    const float* glu_b2    = (const float*)d_in[17];
    const float* W_dec     = (const float*)d_in[18];
    const float* b_dec     = (const float*)d_in[19];
    const float* W_out     = (const float*)d_in[20];
    const float* b_out     = (const float*)d_in[21];

    char* ws = (char*)d_ws;
    const size_t MB = 1 << 20;
    f16*   F0  = (f16*)(ws);             // h1f, later xs_re f16
    f16*   F1  = (f16*)(ws + 16 * MB);   // xs_im f16 (negated)
    f16*   F2  = (f16*)(ws + 32 * MB);   // skipf, later h3f
    f16*   F3  = (f16*)(ws + 48 * MB);   // hnf, later h2f
    float* BuR = (float*)(ws + 64 * MB); // fp32 Bu real (32MB)
    float* BuI = (float*)(ws + 96 * MB); // fp32 Bu imag (32MB)
    f16*   GF  = (f16*)(ws + 64 * MB);   // g (aliases BuR, dead by then)
    f16*   XF  = (f16*)(ws + 128 * MB);  // x in f16 (4MB)
    float* S1  = (float*)(ws + 132 * MB);
    float* G   = (float*)(ws + 134 * MB);
    float* cst = (float*)(ws + 136 * MB);
    f16*   wbuf = (f16*)(ws + 137 * MB);
    f16* WFIN  = wbuf;                 // 65536
    f16* WFENC = WFIN  + 65536;        // 262144
    f16* BFRE  = WFENC + 262144;
    f16* BFIM  = BFRE  + 262144;
    f16* CFRE  = BFIM  + 262144;
    f16* CFIM  = CFRE  + 262144;
    f16* W1F   = CFIM  + 262144;
    f16* W2F   = W1F   + 262144;
    f16* WFDEC = W2F   + 262144;
    f16* WFOUT = WFDEC + 262144;       // 65536

    CvtJobs jobs;
    jobs.j[0]  = {x,      XF,    Mrows * Hin};
    jobs.j[1]  = {W_in,   WFIN,  Dm * Hin};
    jobs.j[2]  = {W_enc,  WFENC, Dm * Dm};
    jobs.j[3]  = {B_re,   BFRE,  Dm * Dm};
    jobs.j[4]  = {B_im,   BFIM,  Dm * Dm};
    jobs.j[5]  = {C_re,   CFRE,  Dm * Dm};
    jobs.j[6]  = {C_im,   CFIM,  Dm * Dm};
    jobs.j[7]  = {glu_w1, W1F,   Dm * Dm};
    jobs.j[8]  = {glu_w2, W2F,   Dm * Dm};
    jobs.j[9]  = {W_dec,  WFDEC, Dm * Dm};
    jobs.j[10] = {W_out,  WFOUT, Hin * Dm};

    convert_k<<<dim3((Mrows * Hin) / 1024, 11), 256, 0, stream>>>(jobs);
    consts_k<<<1, Dm, 0, stream>>>(A_diag, log_steps, cst);

    dim3 blk(256);
    dim3 g512(Mrows / 128, Dm / 128);   // (128, 4)
    dim3 g128(Mrows / 128, Hin / 128);  // (128, 1)

    // h1f = x @ W_in^T + b_in
    gemm_mfma<0, 1><<<g512, blk, 0, stream>>>(XF, nullptr, WFIN, nullptr, b_in, nullptr,
                                              nullptr, nullptr, F0, nullptr, Mrows, Dm, Hin);
    // skipf = h1f @ W_enc^T + b_enc
    gemm_mfma<0, 1><<<g512, blk, 0, stream>>>(F0, nullptr, WFENC, nullptr, b_enc, nullptr,
                                              nullptr, nullptr, F2, nullptr, Mrows, Dm, Dm);
    // hnf = layernorm(skipf)
    layernorm_f16<<<Mrows / 4, 256, 0, stream>>>(F2, ln_g, ln_b, F3);
    // Bu dual projection (fp32 for the scan)
    gemm_mfma<3, 0><<<g512, blk, 0, stream>>>(F3, nullptr, BFRE, BFIM, nullptr, nullptr,
                                              nullptr, nullptr, BuR, BuI, Mrows, Dm, Dm);
    // LinOSS scan (fp32 state), xs out as f16 (imag negated)
    scan_phase1<<<Bb * NC, 512, 0, stream>>>(BuR, BuI, cst, S1);
    scan_phase2<<<(Bb * Dm) / 256, 256, 0, stream>>>(S1, cst, G);
    scan_phase3<<<Bb * NC, 512, 0, stream>>>(BuR, BuI, cst, G, F0, F1);
    // g = gelu(xs_re@C_re^T - xs_im@C_im^T + D*hn)
    gemm_mfma<1, 1><<<g512, blk, 0, stream>>>(F0, F1, CFRE, CFIM, nullptr, nullptr,
                                              F3, Dv, GF, nullptr, Mrows, Dm, Dm);
    // h2f = skip + (g@w1^T+b1)*sigmoid(g@w2^T+b2)
    gemm_mfma<2, 1><<<g512, blk, 0, stream>>>(GF, nullptr, W1F, W2F, glu_b1, glu_b2,
                                              F2, nullptr, F3, nullptr, Mrows, Dm, Dm);
    // h3f = h2f @ W_dec^T + b_dec
    gemm_mfma<0, 1><<<g512, blk, 0, stream>>>(F3, nullptr, WFDEC, nullptr, b_dec, nullptr,
                                              nullptr, nullptr, F2, nullptr, Mrows, Dm, Dm);
    // out = h3f @ W_out^T + b_out  (fp32)
    gemm_mfma<0, 0><<<g128, blk, 0, stream>>>(F2, nullptr, WFOUT, nullptr, b_out, nullptr,
                                              nullptr, nullptr, (float*)d_out, nullptr, Mrows, Hin, Dm);
}